// Round 1
// baseline (441.594 us; speedup 1.0000x reference)
//
#include <hip/hip_runtime.h>
#include <hip/hip_fp16.h>

#define RAD 40
#define SEGF 16          // output rows per wave-strip
#define TX 128           // output cols per tile
#define HH 1024
#define WW 1024
#define NSTRIP 64        // HH/SEGF
#define NXT 8            // WW/TX
// scan domain per tile: [x0-RAD, x0+TX+RAD) = 208 cols, padded to 256.
// lane l owns cols 4l..4l+3 of the domain (lanes 0..51 carry data, 52..63 zero)
// -> SINGLE wave-scan per field per row (was 2 chained at TX=256).

__device__ __forceinline__ float wscan64(float v, int lane) {
    #pragma unroll
    for (int d = 1; d < 64; d <<= 1) {
        float n = __shfl_up(v, d, 64);
        if (lane >= d) v += n;
    }
    return v;
}

// ---------------------------------------------------------------------------
// K_A: one wave per (channel, x-tile, y-strip). Vertical sliding sums of
// I, p, I*p, I*I in registers; per-row single wave-scan; writes a,b fp16x2.
// ---------------------------------------------------------------------------
__global__ __launch_bounds__(64, 6)
void fused_ab_kernel(const float* __restrict__ I, const float* __restrict__ p,
                     unsigned int* __restrict__ ab) {
    __shared__ __align__(16) float PF[4][256];
    const int l = threadIdx.x;
    // XCD-contiguous remap: consecutive logical strips (which share 80/96 input
    // rows) land on the same XCD's L2. bijective since gridDim.x % 8 == 0.
    const int nblk = (int)gridDim.x;
    const int bid0 = (int)blockIdx.x;
    const int bid = (bid0 & 7) * (nblk >> 3) + (bid0 >> 3);
    const int strip = bid & (NSTRIP - 1);
    const int xt = (bid >> 6) & (NXT - 1);
    const int c = bid >> 9;
    const int x0 = xt * TX;
    const int y0 = strip * SEGF;
    const size_t plane = (size_t)c * (HH * WW);
    const float* Ib = I + plane;
    const float* pb = p + plane;

    const int g1 = x0 - RAD + 4 * l;     // domain col (mult of 4)
    const bool v1 = (l < 52) && (g1 >= 0) && (g1 < WW);

    // vertical sliding sums [field][k]: 0=I 1=p 2=Ip 3=II
    float s[4][4];
    #pragma unroll
    for (int f = 0; f < 4; ++f)
        #pragma unroll
        for (int k = 0; k < 4; ++k) s[f][k] = 0.f;

    auto ld = [&](const float* base, int y) -> float4 {
        return v1 ? *(const float4*)(base + (size_t)y * WW + g1)
                  : make_float4(0.f, 0.f, 0.f, 0.f);
    };
    auto acc = [&](float4 a, float4 b, float sg) {
        const float* ri = (const float*)&a;
        const float* rp = (const float*)&b;
        #pragma unroll
        for (int k = 0; k < 4; ++k) {
            s[0][k] += sg * ri[k];
            s[1][k] += sg * rp[k];
            s[2][k] += sg * ri[k] * rp[k];
            s[3][k] += sg * ri[k] * ri[k];
        }
    };

    // prime rows [y0-RAD, y0+RAD), 4-row groups for memory-level parallelism
    int yp0 = y0 - RAD; if (yp0 < 0) yp0 = 0;
    int yp1 = y0 + RAD; if (yp1 > HH) yp1 = HH;
    int y = yp0;
    for (; y + 4 <= yp1; y += 4) {
        float4 a0 = ld(Ib, y    ), b0 = ld(pb, y    );
        float4 a1 = ld(Ib, y + 1), b1 = ld(pb, y + 1);
        float4 a2 = ld(Ib, y + 2), b2 = ld(pb, y + 2);
        float4 a3 = ld(Ib, y + 3), b3 = ld(pb, y + 3);
        acc(a0, b0, 1.f); acc(a1, b1, 1.f); acc(a2, b2, 1.f); acc(a3, b3, 1.f);
    }
    for (; y < yp1; ++y) {
        float4 a0 = ld(Ib, y), b0 = ld(pb, y);
        acc(a0, b0, 1.f);
    }

    float4 pi = make_float4(0.f,0.f,0.f,0.f), pq = pi;
    if (y0 + RAD < HH) { pi = ld(Ib, y0 + RAD); pq = ld(pb, y0 + RAD); }

    for (int yy = y0; yy < y0 + SEGF; ++yy) {
        if (yy + RAD < HH) acc(pi, pq, 1.f);
        // prefetch next add-row and this row's sub-row (latency hides under scan)
        float4 ni = make_float4(0.f,0.f,0.f,0.f), nq = ni, si = ni, sq = ni;
        const int yn = yy + 1 + RAD;
        const bool nh = (yn < HH) && (yy + 1 < y0 + SEGF);
        if (nh) { ni = ld(Ib, yn); nq = ld(pb, yn); }
        const int ys = yy - RAD;
        if (ys >= 0) { si = ld(Ib, ys); sq = ld(pb, ys); }

        // single wave-scan per field, prefix -> LDS
        float incl0[4][4];
        #pragma unroll
        for (int f = 0; f < 4; ++f) {
            float c0 = s[f][0];
            float c1 = c0 + s[f][1];
            float c2 = c1 + s[f][2];
            float c3 = c2 + s[f][3];
            float t = wscan64(c3, l);
            float b0 = t - c3;
            incl0[f][0] = b0 + c0; incl0[f][1] = b0 + c1;
            incl0[f][2] = b0 + c2; incl0[f][3] = b0 + c3;
            ((float4*)PF[f])[l] = make_float4(incl0[f][0], incl0[f][1],
                                              incl0[f][2], incl0[f][3]);
        }
        __syncthreads();   // single-wave workgroup: compiler fence, ~free

        int cv_hi = yy + RAD + 1; if (cv_hi > HH) cv_hi = HH;
        int cv_lo = yy - RAD;     if (cv_lo < 0)  cv_lo = 0;
        const float cntV = (float)(cv_hi - cv_lo);

        if (l < 32) {   // 32 lanes cover the 128 output cols
            float4 hi0 = ((const float4*)PF[0])[l + 20];
            float4 hi1 = ((const float4*)PF[1])[l + 20];
            float4 hi2 = ((const float4*)PF[2])[l + 20];
            float4 hi3 = ((const float4*)PF[3])[l + 20];
            const float* h0 = (const float*)&hi0;
            const float* h1 = (const float*)&hi1;
            const float* h2 = (const float*)&hi2;
            const float* h3 = (const float*)&hi3;

            unsigned int outw[4];
            #pragma unroll
            for (int k = 0; k < 4; ++k) {
                const int go = x0 + 4 * l + k;
                float bI  = h0[k] - (incl0[0][k] - s[0][k]);
                float bp  = h1[k] - (incl0[1][k] - s[1][k]);
                float bIp = h2[k] - (incl0[2][k] - s[2][k]);
                float bII = h3[k] - (incl0[3][k] - s[3][k]);
                int hlo = go - RAD;     if (hlo < 0)  hlo = 0;
                int hhi = go + RAD + 1; if (hhi > WW) hhi = WW;
                const float ic = 1.f / (cntV * (float)(hhi - hlo));
                float mI = bI*ic, mp = bp*ic, mIp = bIp*ic, mII = bII*ic;
                float cov = mIp - mI * mp;
                float var = mII - mI * mI;
                float aa = cov / (var + 1e-3f);
                float bbv = mp - aa * mI;
                __half2 h = __float22half2_rn(make_float2(aa, bbv));
                outw[k] = *reinterpret_cast<unsigned int*>(&h);
            }
            ((uint4*)(ab + plane + (size_t)yy * WW))[(x0 >> 2) + l] =
                make_uint4(outw[0], outw[1], outw[2], outw[3]);
        }

        if (ys >= 0) acc(si, sq, -1.f);
        if (nh) { pi = ni; pq = nq; }
        __syncthreads();   // protect next iter's PF writes vs this iter's reads
    }
}

// ---------------------------------------------------------------------------
// K_B: same structure on packed a,b; epilogue out = mean_a * I + mean_b
// ---------------------------------------------------------------------------
__global__ __launch_bounds__(64, 6)
void fused_out_kernel(const unsigned int* __restrict__ ab, const float* __restrict__ I,
                      float* __restrict__ out) {
    __shared__ __align__(16) float PF[2][256];
    const int l = threadIdx.x;
    const int nblk = (int)gridDim.x;
    const int bid0 = (int)blockIdx.x;
    const int bid = (bid0 & 7) * (nblk >> 3) + (bid0 >> 3);
    const int strip = bid & (NSTRIP - 1);
    const int xt = (bid >> 6) & (NXT - 1);
    const int c = bid >> 9;
    const int x0 = xt * TX;
    const int y0 = strip * SEGF;
    const size_t plane = (size_t)c * (HH * WW);
    const unsigned int* abp = ab + plane;

    const int g1 = x0 - RAD + 4 * l;
    const bool v1 = (l < 52) && (g1 >= 0) && (g1 < WW);

    float s[2][4];
    #pragma unroll
    for (int f = 0; f < 2; ++f)
        #pragma unroll
        for (int k = 0; k < 4; ++k) s[f][k] = 0.f;

    auto ld2 = [&](int y, float* ra, float* rb) {
        uint4 A = v1 ? *(const uint4*)(abp + (size_t)y * WW + g1)
                     : make_uint4(0u, 0u, 0u, 0u);
        const unsigned int* aw = (const unsigned int*)&A;
        #pragma unroll
        for (int k = 0; k < 4; ++k) {
            __half2 h = *reinterpret_cast<const __half2*>(&aw[k]);
            float2 f2 = __half22float2(h);
            ra[k] = f2.x; rb[k] = f2.y;
        }
    };
    auto acc2 = [&](const float* ra, const float* rb, float sg) {
        #pragma unroll
        for (int k = 0; k < 4; ++k) {
            s[0][k] += sg * ra[k];
            s[1][k] += sg * rb[k];
        }
    };

    int yp0 = y0 - RAD; if (yp0 < 0) yp0 = 0;
    int yp1 = y0 + RAD; if (yp1 > HH) yp1 = HH;
    int y = yp0;
    for (; y + 4 <= yp1; y += 4) {
        float ra[4][4], rb[4][4];
        ld2(y    , ra[0], rb[0]);
        ld2(y + 1, ra[1], rb[1]);
        ld2(y + 2, ra[2], rb[2]);
        ld2(y + 3, ra[3], rb[3]);
        acc2(ra[0], rb[0], 1.f); acc2(ra[1], rb[1], 1.f);
        acc2(ra[2], rb[2], 1.f); acc2(ra[3], rb[3], 1.f);
    }
    for (; y < yp1; ++y) {
        float ra[4], rb[4];
        ld2(y, ra, rb);
        acc2(ra, rb, 1.f);
    }

    float pa[4] = {0.f,0.f,0.f,0.f}, pbv[4] = {0.f,0.f,0.f,0.f};
    if (y0 + RAD < HH) ld2(y0 + RAD, pa, pbv);

    for (int yy = y0; yy < y0 + SEGF; ++yy) {
        if (yy + RAD < HH) acc2(pa, pbv, 1.f);
        float na[4] = {0.f,0.f,0.f,0.f}, nb[4] = {0.f,0.f,0.f,0.f};
        float sa[4] = {0.f,0.f,0.f,0.f}, sb[4] = {0.f,0.f,0.f,0.f};
        const int yn = yy + 1 + RAD;
        const bool nh = (yn < HH) && (yy + 1 < y0 + SEGF);
        if (nh) ld2(yn, na, nb);
        const int ys = yy - RAD;
        if (ys >= 0) ld2(ys, sa, sb);

        float incl0[2][4];
        #pragma unroll
        for (int f = 0; f < 2; ++f) {
            float c0 = s[f][0];
            float c1 = c0 + s[f][1];
            float c2 = c1 + s[f][2];
            float c3 = c2 + s[f][3];
            float t = wscan64(c3, l);
            float b0 = t - c3;
            incl0[f][0] = b0 + c0; incl0[f][1] = b0 + c1;
            incl0[f][2] = b0 + c2; incl0[f][3] = b0 + c3;
            ((float4*)PF[f])[l] = make_float4(incl0[f][0], incl0[f][1],
                                              incl0[f][2], incl0[f][3]);
        }
        __syncthreads();

        int cv_hi = yy + RAD + 1; if (cv_hi > HH) cv_hi = HH;
        int cv_lo = yy - RAD;     if (cv_lo < 0)  cv_lo = 0;
        const float cntV = (float)(cv_hi - cv_lo);

        if (l < 32) {
            float4 hiA = ((const float4*)PF[0])[l + 20];
            float4 hiB = ((const float4*)PF[1])[l + 20];
            const float* hA = (const float*)&hiA;
            const float* hB = (const float*)&hiB;
            float4 Iv = ((const float4*)(I + plane + (size_t)yy * WW))[(x0 >> 2) + l];
            const float* Ik = (const float*)&Iv;

            float oo[4];
            #pragma unroll
            for (int k = 0; k < 4; ++k) {
                const int go = x0 + 4 * l + k;
                float ba = hA[k] - (incl0[0][k] - s[0][k]);
                float bb = hB[k] - (incl0[1][k] - s[1][k]);
                int hlo = go - RAD;     if (hlo < 0)  hlo = 0;
                int hhi = go + RAD + 1; if (hhi > WW) hhi = WW;
                const float ic = 1.f / (cntV * (float)(hhi - hlo));
                oo[k] = (ba * ic) * Ik[k] + bb * ic;
            }
            ((float4*)(out + plane + (size_t)yy * WW))[(x0 >> 2) + l] =
                make_float4(oo[0], oo[1], oo[2], oo[3]);
        }

        if (ys >= 0) acc2(sa, sb, -1.f);
        if (nh) {
            #pragma unroll
            for (int k = 0; k < 4; ++k) { pa[k] = na[k]; pbv[k] = nb[k]; }
        }
        __syncthreads();
    }
}

extern "C" void kernel_launch(void* const* d_in, const int* in_sizes, int n_in,
                              void* d_out, int out_size, void* d_ws, size_t ws_size,
                              hipStream_t stream) {
    const float* I = (const float*)d_in[0];
    const float* p = (const float*)d_in[1];
    float* out = (float*)d_out;

    const int N = in_sizes[0];           // B*C*H*W
    const int BC = N / (HH * WW);

    unsigned int* ab = (unsigned int*)d_ws;   // fp16x2 {a,b} per pixel

    const int nblk = BC * NXT * NSTRIP;  // BC * 8 * 64
    fused_ab_kernel<<<dim3(nblk), 64, 0, stream>>>(I, p, ab);
    fused_out_kernel<<<dim3(nblk), 64, 0, stream>>>(ab, I, out);
}